// Round 9
// baseline (1578.761 us; speedup 1.0000x reference)
//
#include <hip/hip_runtime.h>
#include <hip/hip_bf16.h>

#define NF 128
#define RBF 20

using short8 = __attribute__((ext_vector_type(8))) short;
using f32x4  = __attribute__((ext_vector_type(4))) float;

__device__ __forceinline__ float sspf(float v) {
    return fmaxf(v, 0.f) + log1pf(__expf(-fabsf(v))) - 0.69314718055994531f;
}
__device__ __forceinline__ unsigned short f2bf(float f) {
    union { float f; unsigned u; } v; v.f = f;
    unsigned r = v.u + 0x7fffu + ((v.u >> 16) & 1u);
    return (unsigned short)(r >> 16);
}
__device__ __forceinline__ float bf2f(unsigned short s) {
    union { unsigned u; float f; } v; v.u = ((unsigned)s) << 16;
    return v.f;
}

// ---------------------------------------------------------------------------
// Sort machinery: counting sort of edges by idx_i and idx_j.
// ---------------------------------------------------------------------------
__global__ void hist_kernel(const int* __restrict__ idx_i,
                            const int* __restrict__ idx_j,
                            int* __restrict__ deg_i, int* __restrict__ deg_j, int E)
{
    for (int e = blockIdx.x * blockDim.x + threadIdx.x; e < E;
         e += gridDim.x * blockDim.x) {
        atomicAdd(&deg_i[idx_i[e]], 1);
        atomicAdd(&deg_j[idx_j[e]], 1);
    }
}

// per-2048-chunk exclusive scan; block totals to parts[y*64+bx]
__global__ void scanA_kernel(const int* __restrict__ deg_i, const int* __restrict__ deg_j,
                             int* __restrict__ loc_i, int* __restrict__ loc_j,
                             int* __restrict__ parts, int NN)
{
    const int y = blockIdx.y;
    const int* deg = y ? deg_j : deg_i;
    int* loc       = y ? loc_j : loc_i;
    const int tid = threadIdx.x;
    const int base = blockIdx.x * 2048;

    __shared__ int tsum[256];
    int v[8]; int s = 0;
    #pragma unroll
    for (int r = 0; r < 8; ++r) {
        const int idx = base + tid * 8 + r;
        v[r] = (idx < NN) ? deg[idx] : 0;
        s += v[r];
    }
    tsum[tid] = s;
    __syncthreads();
    #pragma unroll
    for (int d = 1; d < 256; d <<= 1) {
        const int add = (tid >= d) ? tsum[tid - d] : 0;
        __syncthreads();
        tsum[tid] += add;
        __syncthreads();
    }
    int run = tsum[tid] - s;          // exclusive thread base
    #pragma unroll
    for (int r = 0; r < 8; ++r) {
        const int idx = base + tid * 8 + r;
        if (idx < NN) loc[idx] = run;
        run += v[r];
    }
    if (tid == 0) parts[y * 64 + blockIdx.x] = tsum[255];
}

__global__ void scanB_kernel(int* __restrict__ parts, int NB)
{
    __shared__ int p[2][64];
    const int t = threadIdx.x & 63, a = threadIdx.x >> 6;
    p[a][t] = (t < NB) ? parts[a * 64 + t] : 0;
    __syncthreads();
    #pragma unroll
    for (int d = 1; d < 64; d <<= 1) {
        const int add = (t >= d) ? p[a][t - d] : 0;
        __syncthreads();
        p[a][t] += add;
        __syncthreads();
    }
    parts[a * 64 + t] = (t > 0) ? p[a][t - 1] : 0;
}

__global__ void scanC_kernel(const int* __restrict__ loc_i, const int* __restrict__ loc_j,
                             const int* __restrict__ parts,
                             int* __restrict__ rowp_i, int* __restrict__ rowp_j,
                             int* __restrict__ cur_i, int* __restrict__ cur_j, int NN)
{
    const int y = blockIdx.y;
    const int* loc = y ? loc_j : loc_i;
    const int* pb  = parts + y * 64;
    int* rowp = y ? rowp_j : rowp_i;
    int* cur  = y ? cur_j  : cur_i;
    for (int i = blockIdx.x * blockDim.x + threadIdx.x; i < NN;
         i += gridDim.x * blockDim.x) {
        const int v = loc[i] + pb[i >> 11];
        rowp[i] = v;
        cur[i]  = v;
    }
}

__global__ void scatter_kernel(const int* __restrict__ idx_i, const int* __restrict__ idx_j,
                               int* __restrict__ cur_i, int* __restrict__ cur_j,
                               int* __restrict__ ord_i, int* __restrict__ ord_j, int E)
{
    for (int e = blockIdx.x * blockDim.x + threadIdx.x; e < E;
         e += gridDim.x * blockDim.x) {
        const int pi = atomicAdd(&cur_i[idx_i[e]], 1);
        ord_i[pi] = e;
        const int pj = atomicAdd(&cur_j[idx_j[e]], 1);
        ord_j[pj] = e;
    }
}

// ---------------------------------------------------------------------------
// Edge pass (per sort order): block owns 16 nodes; per 64-edge tile:
//  MFMA filter-MLP -> wij LDS -> cooperative gather staging -> segmented
//  column scan -> plain fp32 store into conv. NO ATOMICS.
// ---------------------------------------------------------------------------
__global__ __launch_bounds__(256, 4)
void edge_pass_kernel(const float* __restrict__ f_ij,
                      const float* __restrict__ rcut,
                      const float* __restrict__ Wf1,
                      const float* __restrict__ bf1,
                      const float* __restrict__ Wf2,
                      const float* __restrict__ bf2v,
                      const unsigned short* __restrict__ gat,   // yf (pass-x) / xf (pass-y)
                      const int* __restrict__ idx_own,          // idx_i / idx_j
                      const int* __restrict__ idx_oth,          // idx_j / idx_i
                      const int* __restrict__ ord,
                      const int* __restrict__ rowp,
                      float* __restrict__ conv,
                      int NN, int E)
{
    const int tid = threadIdx.x;
    const int l = tid & 63, w = tid >> 6;
    const int lr = l & 15, lk = l >> 4;
    const int wcol0 = w * 32;

    __shared__ unsigned short f16[64 * 40];     // 5.1 KB (K padded, stride 40)
    __shared__ unsigned short Ash[64 * NF];     // 16 KB: h (swizzled), then gathers
    __shared__ unsigned short wij_s[64 * 136];  // 17.4 KB (pad 8)
    __shared__ int jo_s[64];
    __shared__ int ni_s[65];
    __shared__ float rc_s[64];

    // persistent weight fragments
    short8 b1fr[2];
    #pragma unroll
    for (int cb = 0; cb < 2; ++cb) {
        const int col = wcol0 + cb * 16 + lr;
        #pragma unroll
        for (int j = 0; j < 8; ++j) {
            const int k = lk * 8 + j;
            b1fr[cb][j] = (k < RBF) ? (short)f2bf(Wf1[k * NF + col]) : (short)0;
        }
    }
    short8 b2fr[4][2];
    #pragma unroll
    for (int kb = 0; kb < 4; ++kb)
        #pragma unroll
        for (int cb = 0; cb < 2; ++cb) {
            const int col = wcol0 + cb * 16 + lr;
            #pragma unroll
            for (int j = 0; j < 8; ++j)
                b2fr[kb][cb][j] = (short)f2bf(Wf2[(size_t)(kb * 32 + lk * 8 + j) * NF + col]);
        }
    const float b1c0 = bf1[wcol0 + lr],  b1c1 = bf1[wcol0 + 16 + lr];
    const float b2c0 = bf2v[wcol0 + lr], b2c1 = bf2v[wcol0 + 16 + lr];

    const int n0 = blockIdx.x * 16;
    const int eb = rowp[n0];
    const int ee = (n0 + 16 < NN) ? rowp[n0 + 16] : E;

    // zero conv rows [n0, n0+16)  (16*128 = 2048 floats)
    #pragma unroll
    for (int r = 0; r < 8; ++r)
        conv[(size_t)n0 * NF + r * 256 + tid] = 0.f;

    float acc = 0.f;                     // segment carry (scan threads)
    const int c = tid & 127;
    const int nt = (ee - eb + 63) >> 6;

    for (int t = 0; t < nt; ++t) {
        const int p0 = eb + t * 64;
        __syncthreads();                 // prev-tile scan readers done

        // stage meta (slots 0..64)
        if (tid < 65) {
            const int p = p0 + tid;
            const bool val = p < ee;
            const int e = val ? ord[p] : 0;
            ni_s[tid] = val ? idx_own[e] : -1;
            if (tid < 64) {
                jo_s[tid] = val ? idx_oth[e] * NF : 0;
                rc_s[tid] = val ? rcut[e] : 0.f;
            }
        }
        // stage f tile (gathered rows), K padded to 32, row stride 40
        #pragma unroll
        for (int s8 = 0; s8 < 8; ++s8) {
            const int tt = s8 * 256 + tid;
            const int row = tt >> 5, k = tt & 31;
            const int p = p0 + row;
            float v = 0.f;
            if (k < RBF && p < ee) v = f_ij[(size_t)ord[p] * RBF + k];
            f16[row * 40 + k] = f2bf(v);
        }
        __syncthreads();

        // phase 1: h = ssp(f @ W1 + b1)
        f32x4 acc1[4][2] = {};
        #pragma unroll
        for (int rb = 0; rb < 4; ++rb) {
            const short8 a = *reinterpret_cast<const short8*>(
                &f16[(rb * 16 + lr) * 40 + lk * 8]);
            acc1[rb][0] = __builtin_amdgcn_mfma_f32_16x16x32_bf16(a, b1fr[0], acc1[rb][0], 0, 0, 0);
            acc1[rb][1] = __builtin_amdgcn_mfma_f32_16x16x32_bf16(a, b1fr[1], acc1[rb][1], 0, 0, 0);
        }
        #pragma unroll
        for (int rb = 0; rb < 4; ++rb)
            #pragma unroll
            for (int cb = 0; cb < 2; ++cb) {
                const int col = wcol0 + cb * 16 + lr;
                #pragma unroll
                for (int q = 0; q < 4; ++q) {
                    const int e = rb * 16 + lk * 4 + q;
                    const float hv = sspf(acc1[rb][cb][q] + (cb ? b1c1 : b1c0));
                    Ash[e * NF + (col ^ ((e & 7) << 3))] = f2bf(hv);
                }
            }
        __syncthreads();

        // phase 2: wij = (h @ W2 + b2) * rcut -> LDS
        f32x4 acc2[4][2] = {};
        #pragma unroll
        for (int rb = 0; rb < 4; ++rb) {
            short8 a[4];
            #pragma unroll
            for (int kb = 0; kb < 4; ++kb) {
                const int e  = rb * 16 + lr;
                const int k0 = kb * 32 + lk * 8;
                a[kb] = *reinterpret_cast<const short8*>(
                    &Ash[e * NF + (k0 ^ ((e & 7) << 3))]);
            }
            #pragma unroll
            for (int cb = 0; cb < 2; ++cb)
                #pragma unroll
                for (int kb = 0; kb < 4; ++kb)
                    acc2[rb][cb] = __builtin_amdgcn_mfma_f32_16x16x32_bf16(
                        a[kb], b2fr[kb][cb], acc2[rb][cb], 0, 0, 0);
        }
        __syncthreads();                 // all Ash(h) reads done

        #pragma unroll
        for (int rb = 0; rb < 4; ++rb)
            #pragma unroll
            for (int cb = 0; cb < 2; ++cb) {
                const int col = wcol0 + cb * 16 + lr;
                const float bb = cb ? b2c1 : b2c0;
                #pragma unroll
                for (int q = 0; q < 4; ++q) {
                    const int e = rb * 16 + lk * 4 + q;
                    wij_s[e * 136 + col] = f2bf((acc2[rb][cb][q] + bb) * rc_s[e]);
                }
            }

        // stage gathered feature rows into Ash (reuse): 64 rows x 128 bf16
        #pragma unroll
        for (int u = 0; u < 16; ++u) {
            const int tt = u * 256 + tid;
            const int slot = tt >> 6, cp = tt & 63;
            const unsigned v = reinterpret_cast<const unsigned*>(gat)[(jo_s[slot] >> 1) + cp];
            reinterpret_cast<unsigned*>(Ash)[slot * 64 + cp] = v;
        }
        __syncthreads();

        // segmented scan: 128 threads, one column each, sequential over slots
        if (tid < 128) {
            const int cnt = min(64, ee - p0);
            #pragma unroll 4
            for (int s = 0; s < cnt; ++s) {
                const float wv = bf2f(wij_s[s * 136 + c]);
                const float g  = bf2f(Ash[s * NF + c]);
                acc = fmaf(g, wv, acc);
                if (ni_s[s + 1] != ni_s[s]) {
                    conv[(size_t)ni_s[s] * NF + c] = acc;
                    acc = 0.f;
                }
            }
        }
    }
}

// ---------------------------------------------------------------------------
// Projection (persistent): out_bf16 = in @ W (bias-free)
// ---------------------------------------------------------------------------
__global__ __launch_bounds__(256, 2)
void proj_mfma_kernel(const float* in0, const float* in1,
                      const float* __restrict__ W0, const float* __restrict__ W1p,
                      unsigned short* o0, unsigned short* o1, int N, int nTiles)
{
    const float* in = blockIdx.y ? in1 : in0;
    const float* W  = blockIdx.y ? W1p : W0;
    unsigned short* out = blockIdx.y ? o1 : o0;

    const int tid = threadIdx.x;
    const int l = tid & 63, w = tid >> 6;
    const int lr = l & 15, lk = l >> 4;
    const int wcol0 = w * 32;

    __shared__ unsigned short Ahi[64 * NF];

    short8 bfr[4][2];
    #pragma unroll
    for (int kb = 0; kb < 4; ++kb)
        #pragma unroll
        for (int cb = 0; cb < 2; ++cb) {
            const int col = wcol0 + cb * 16 + lr;
            #pragma unroll
            for (int j = 0; j < 8; ++j)
                bfr[kb][cb][j] = (short)f2bf(W[(size_t)(kb * 32 + lk * 8 + j) * NF + col]);
        }

    for (int tile = blockIdx.x; tile < nTiles; tile += gridDim.x) {
        const int n0 = tile * 64;
        __syncthreads();
        #pragma unroll
        for (int s = 0; s < 32; ++s) {
            const int t = s * 256 + tid;
            const int row = t >> 7, cc = t & (NF - 1);
            const float v = (n0 + row < N) ? in[(size_t)(n0 + row) * NF + cc] : 0.f;
            Ahi[row * NF + (cc ^ ((row & 7) << 3))] = f2bf(v);
        }
        __syncthreads();

        f32x4 acc[4][2] = {};
        #pragma unroll
        for (int rb = 0; rb < 4; ++rb) {
            short8 a[4];
            #pragma unroll
            for (int kb = 0; kb < 4; ++kb) {
                const int e  = rb * 16 + lr;
                const int k0 = kb * 32 + lk * 8;
                a[kb] = *reinterpret_cast<const short8*>(&Ahi[e * NF + (k0 ^ ((e & 7) << 3))]);
            }
            #pragma unroll
            for (int cb = 0; cb < 2; ++cb)
                #pragma unroll
                for (int kb = 0; kb < 4; ++kb)
                    acc[rb][cb] = __builtin_amdgcn_mfma_f32_16x16x32_bf16(
                        a[kb], bfr[kb][cb], acc[rb][cb], 0, 0, 0);
        }

        #pragma unroll
        for (int rb = 0; rb < 4; ++rb)
            #pragma unroll
            for (int cb = 0; cb < 2; ++cb) {
                const int col = wcol0 + cb * 16 + lr;
                #pragma unroll
                for (int q = 0; q < 4; ++q) {
                    const int n = n0 + rb * 16 + lk * 4 + q;
                    if (n < N) out[(size_t)n * NF + col] = f2bf(acc[rb][cb][q]);
                }
            }
    }
}

// ---------------------------------------------------------------------------
// Fused output MLP (persistent): out = ssp(conv @ W1 + b1) @ W2 + b2
// conv fp32; split-bf16 (hi/lo) A for near-fp32 precision.
// ---------------------------------------------------------------------------
__global__ __launch_bounds__(256, 2)
void out_fused_kernel(const float* conv0, const float* conv1,
                      const float* __restrict__ W10, const float* __restrict__ W11,
                      const float* __restrict__ b10, const float* __restrict__ b11,
                      const float* __restrict__ W20, const float* __restrict__ W21,
                      const float* __restrict__ b20, const float* __restrict__ b21,
                      float* o0, float* o1, int N, int nTiles)
{
    const float* in = blockIdx.y ? conv1 : conv0;
    const float* W1 = blockIdx.y ? W11 : W10;
    const float* b1 = blockIdx.y ? b11 : b10;
    const float* W2 = blockIdx.y ? W21 : W20;
    const float* b2 = blockIdx.y ? b21 : b20;
    float* out      = blockIdx.y ? o1  : o0;

    const int tid = threadIdx.x;
    const int l = tid & 63, w = tid >> 6;
    const int lr = l & 15, lk = l >> 4;
    const int wcol0 = w * 32;

    __shared__ unsigned short Ahi[64 * NF];
    __shared__ unsigned short Alo[64 * NF];

    short8 w1fr[4][2], w2fr[4][2];
    #pragma unroll
    for (int kb = 0; kb < 4; ++kb)
        #pragma unroll
        for (int cb = 0; cb < 2; ++cb) {
            const int col = wcol0 + cb * 16 + lr;
            #pragma unroll
            for (int j = 0; j < 8; ++j) {
                const size_t kk = (size_t)(kb * 32 + lk * 8 + j) * NF + col;
                w1fr[kb][cb][j] = (short)f2bf(W1[kk]);
                w2fr[kb][cb][j] = (short)f2bf(W2[kk]);
            }
        }
    const float b1c0 = b1[wcol0 + lr], b1c1 = b1[wcol0 + 16 + lr];
    const float b2c0 = b2[wcol0 + lr], b2c1 = b2[wcol0 + 16 + lr];

    for (int tile = blockIdx.x; tile < nTiles; tile += gridDim.x) {
        const int n0 = tile * 64;
        __syncthreads();
        #pragma unroll
        for (int s = 0; s < 32; ++s) {
            const int t = s * 256 + tid;
            const int row = t >> 7, cc = t & (NF - 1);
            const float v = (n0 + row < N) ? in[(size_t)(n0 + row) * NF + cc] : 0.f;
            const unsigned short hi = f2bf(v);
            const int idx = row * NF + (cc ^ ((row & 7) << 3));
            Ahi[idx] = hi;
            Alo[idx] = f2bf(v - bf2f(hi));
        }
        __syncthreads();

        f32x4 acc1[4][2] = {};
        #pragma unroll
        for (int rb = 0; rb < 4; ++rb) {
            short8 ah[4], al[4];
            #pragma unroll
            for (int kb = 0; kb < 4; ++kb) {
                const int e  = rb * 16 + lr;
                const int k0 = kb * 32 + lk * 8;
                const int idx = e * NF + (k0 ^ ((e & 7) << 3));
                ah[kb] = *reinterpret_cast<const short8*>(&Ahi[idx]);
                al[kb] = *reinterpret_cast<const short8*>(&Alo[idx]);
            }
            #pragma unroll
            for (int cb = 0; cb < 2; ++cb)
                #pragma unroll
                for (int kb = 0; kb < 4; ++kb) {
                    acc1[rb][cb] = __builtin_amdgcn_mfma_f32_16x16x32_bf16(
                        ah[kb], w1fr[kb][cb], acc1[rb][cb], 0, 0, 0);
                    acc1[rb][cb] = __builtin_amdgcn_mfma_f32_16x16x32_bf16(
                        al[kb], w1fr[kb][cb], acc1[rb][cb], 0, 0, 0);
                }
        }
        __syncthreads();

        #pragma unroll
        for (int rb = 0; rb < 4; ++rb)
            #pragma unroll
            for (int cb = 0; cb < 2; ++cb) {
                const int col = wcol0 + cb * 16 + lr;
                #pragma unroll
                for (int q = 0; q < 4; ++q) {
                    const int e = rb * 16 + lk * 4 + q;
                    const float hv = sspf(acc1[rb][cb][q] + (cb ? b1c1 : b1c0));
                    const unsigned short hi = f2bf(hv);
                    const int idx = e * NF + (col ^ ((e & 7) << 3));
                    Ahi[idx] = hi;
                    Alo[idx] = f2bf(hv - bf2f(hi));
                }
            }
        __syncthreads();

        f32x4 acc2[4][2] = {};
        #pragma unroll
        for (int rb = 0; rb < 4; ++rb) {
            short8 ah[4], al[4];
            #pragma unroll
            for (int kb = 0; kb < 4; ++kb) {
                const int e  = rb * 16 + lr;
                const int k0 = kb * 32 + lk * 8;
                const int idx = e * NF + (k0 ^ ((e & 7) << 3));
                ah[kb] = *reinterpret_cast<const short8*>(&Ahi[idx]);
                al[kb] = *reinterpret_cast<const short8*>(&Alo[idx]);
            }
            #pragma unroll
            for (int cb = 0; cb < 2; ++cb)
                #pragma unroll
                for (int kb = 0; kb < 4; ++kb) {
                    acc2[rb][cb] = __builtin_amdgcn_mfma_f32_16x16x32_bf16(
                        ah[kb], w2fr[kb][cb], acc2[rb][cb], 0, 0, 0);
                    acc2[rb][cb] = __builtin_amdgcn_mfma_f32_16x16x32_bf16(
                        al[kb], w2fr[kb][cb], acc2[rb][cb], 0, 0, 0);
                }
        }

        #pragma unroll
        for (int rb = 0; rb < 4; ++rb)
            #pragma unroll
            for (int cb = 0; cb < 2; ++cb) {
                const int col = wcol0 + cb * 16 + lr;
                #pragma unroll
                for (int q = 0; q < 4; ++q) {
                    const int n = n0 + rb * 16 + lk * 4 + q;
                    if (n < N)
                        out[(size_t)n * NF + col] = acc2[rb][cb][q] + (cb ? b2c1 : b2c0);
                }
            }
    }
}

extern "C" void kernel_launch(void* const* d_in, const int* in_sizes, int n_in,
                              void* d_out, int out_size, void* d_ws, size_t ws_size,
                              hipStream_t stream)
{
    const float* x    = (const float*)d_in[0];
    const float* y    = (const float*)d_in[1];
    const float* f_ij = (const float*)d_in[2];
    const float* rcut = (const float*)d_in[3];
    const int* idx_i  = (const int*)d_in[4];
    const int* idx_j  = (const int*)d_in[5];
    const float* W_in2f   = (const float*)d_in[6];
    const float* W_in2f_y = (const float*)d_in[7];
    const float* Wf1 = (const float*)d_in[8];
    const float* bf1 = (const float*)d_in[9];
    const float* Wf2 = (const float*)d_in[10];
    const float* bf2 = (const float*)d_in[11];
    const float* Wx1 = (const float*)d_in[12];
    const float* bx1 = (const float*)d_in[13];
    const float* Wx2 = (const float*)d_in[14];
    const float* bx2 = (const float*)d_in[15];
    const float* Wy1 = (const float*)d_in[16];
    const float* by1 = (const float*)d_in[17];
    const float* Wy2 = (const float*)d_in[18];
    const float* by2 = (const float*)d_in[19];

    const int N = in_sizes[0] / NF;
    const int E = in_sizes[4];
    const size_t NNF = (size_t)N * NF;

    // d_out layout: [0, 4N*NF B): xf,yf bf16 (dead after edge passes);
    //               upper half: sort scratch (dead before out_fused writes).
    unsigned short* xf = (unsigned short*)d_out;
    unsigned short* yf = xf + NNF;
    float* ox = (float*)d_out;
    float* oy = ox + NNF;

    int* sb     = (int*)((char*)d_out + 4 * NNF);
    int* deg_i  = sb;
    int* deg_j  = sb + N;
    int* loc_i  = sb + 2 * N;
    int* loc_j  = sb + 3 * N;
    int* rowp_i = sb + 4 * N;
    int* rowp_j = sb + 5 * N;
    int* cur_i  = sb + 6 * N;
    int* cur_j  = sb + 7 * N;
    int* parts  = sb + 8 * N;          // 128 ints
    int* ord_i  = sb + 8 * N + 256;
    int* ord_j  = ord_i + E;

    float* conv_x = (float*)d_ws;       // fp32, written by plain stores
    float* conv_y = conv_x + NNF;

    const int NB = (N + 2047) / 2048;
    const int nodeTiles = (N + 63) / 64;
    const int nodeGroups = (N + 15) / 16;

    hipMemsetAsync(deg_i, 0, (size_t)2 * N * sizeof(int), stream);

    proj_mfma_kernel<<<dim3(1024, 2), 256, 0, stream>>>(
        x, y, W_in2f, W_in2f_y, xf, yf, N, nodeTiles);

    hist_kernel<<<1024, 256, 0, stream>>>(idx_i, idx_j, deg_i, deg_j, E);
    scanA_kernel<<<dim3(NB, 2), 256, 0, stream>>>(deg_i, deg_j, loc_i, loc_j, parts, N);
    scanB_kernel<<<1, 128, 0, stream>>>(parts, NB);
    scanC_kernel<<<dim3(128, 2), 256, 0, stream>>>(loc_i, loc_j, parts,
        rowp_i, rowp_j, cur_i, cur_j, N);
    scatter_kernel<<<1024, 256, 0, stream>>>(idx_i, idx_j, cur_i, cur_j, ord_i, ord_j, E);

    // pass-x: edges sorted by idx_i, gather yf, write conv_x
    edge_pass_kernel<<<nodeGroups, 256, 0, stream>>>(
        f_ij, rcut, Wf1, bf1, Wf2, bf2, yf, idx_i, idx_j,
        ord_i, rowp_i, conv_x, N, E);
    // pass-y: edges sorted by idx_j, gather xf, write conv_y
    edge_pass_kernel<<<nodeGroups, 256, 0, stream>>>(
        f_ij, rcut, Wf1, bf1, Wf2, bf2, xf, idx_j, idx_i,
        ord_j, rowp_j, conv_y, N, E);

    out_fused_kernel<<<dim3(1024, 2), 256, 0, stream>>>(
        conv_x, conv_y, Wx1, Wy1, bx1, by1, Wx2, Wy2, bx2, by2,
        ox, oy, N, nodeTiles);
}